// Round 6
// baseline (259.388 us; speedup 1.0000x reference)
//
#include <hip/hip_runtime.h>
#include <hip/hip_bf16.h>

// InstanceAttentionModule: B=32, H=W=32 (HW=1024), C=256, F=64, K_NEIGH=32.
// Round-14: occupancy attack on k_out2. Round-4 structure (fused R+scores+PV,
// recompute-gram, XCD locality) was 2 blocks/CU ONLY because grid=512 capped
// it. New shape: 32-row tiles -> grid 1024 = exactly 4 blocks/CU resident.
//   - Kb DELETED: gram jf operands load direct from L2 (embb 128KB/batch is
//     L2-hot; round-3 k_R's proven pattern) -> LDS 51.7 -> ~38.4KB (fits 4/CU)
//   - wave roles: wr=w&1 (row-half), wj=w>>1 (j-half). Pass-0 barrier-free
//     j-half sweep; R = rtmp[0][q]+rtmp[1][q] (1 barrier).
//   - pass-2: per 32-j step each wave produces its 16x16 P quadrant
//     (2 gram MFMA + 4 e/u chains), ONE barrier, PV 8 MFMA (col-quarter).
//   - STAGE_S moved AFTER the barrier (fixes round-4's latent Sb race).
//   - epk register caching (round-13) ABANDONED: compiler scratch-demoted it.
// k_prep, k_lin unchanged.

typedef short bf16x8 __attribute__((ext_vector_type(8)));
typedef float f32x4 __attribute__((ext_vector_type(4)));

#define LOG2E 1.4426950408889634f

__device__ __forceinline__ unsigned short f2bf(float f) {
  unsigned u = __float_as_uint(f);
  u += 0x7fffu + ((u >> 16) & 1u);   // round-to-nearest-even
  return (unsigned short)(u >> 16);
}
__device__ __forceinline__ float bf2f(unsigned short h) {
  return __uint_as_float(((unsigned)h) << 16);
}
__device__ __forceinline__ unsigned pack2(float a, float b) {
  return (unsigned)f2bf(a) | ((unsigned)f2bf(b) << 16);
}
__device__ __forceinline__ unsigned cvtpk(float lo, float hi) {
  unsigned r;
  asm("v_cvt_pk_bf16_f32 %0, %1, %2" : "=v"(r) : "v"(lo), "v"(hi));
  return r;
}
__device__ __forceinline__ float exp2x(float x) {   // 2^x, single v_exp_f32
  float r;
  asm("v_exp_f32 %0, %1" : "=v"(r) : "v"(x));
  return r;
}
__device__ __forceinline__ f32x4 mfma16(bf16x8 a, bf16x8 b, f32x4 c) {
  return __builtin_amdgcn_mfma_f32_16x16x32_bf16(a, b, c, 0, 0, 0);
}
__device__ __forceinline__ int iabs(int v) { return v < 0 ? -v : v; }
__device__ __forceinline__ void load_lds16(const void* g, void* l) {
  __builtin_amdgcn_global_load_lds(
      (const __attribute__((address_space(1))) unsigned int*)g,
      (__attribute__((address_space(3))) unsigned int*)l, 16, 0, 0);
}

// e-chain shared by pass-0 (R) and pass-2 (u): same inputs -> same bits
__device__ __forceinline__ float e_chain(float g, float nsq2i, float sq2j,
                                         int diff) {
  float w2 = fminf(fmaf(2.f * LOG2E, g, nsq2i - sq2j), 0.f);
  float fd = (float)diff;
  float fs = (diff <= 32) ? fd : 0.f;
  return exp2x(fmaf(exp2x(w2), LOG2E, fmaf(fs, LOG2E / 32.f, -LOG2E)));
}

// ---------------------------------------------------------------- k_prep
// grid 80 x 256, 4 elems/thread: Wb = bf16(embW rows 0..63 || attnW rows 64..319)
__global__ __launch_bounds__(256) void k_prep(const float* __restrict__ embW,
                                              const float* __restrict__ attnW,
                                              unsigned short* __restrict__ Wb) {
  const int i = (blockIdx.x * 256 + threadIdx.x) * 4;   // 0..81916
  float4 v = (i < 16384) ? *(const float4*)(embW + i)
                         : *(const float4*)(attnW + (i - 16384));
  ushort4 p; p.x = f2bf(v.x); p.y = f2bf(v.y); p.z = f2bf(v.z); p.w = f2bf(v.w);
  *(ushort4*)(Wb + i) = p;
}

// ---------------------------------------------------------------- k_lin
// Fused emb+shortcut. grid 512 (64-row M-tiles), block 256 = 4 waves (2x2).
// sq2 and T2 outputs are PRE-SCALED by log2(e) for the exp2 domain.
__global__ __launch_bounds__(256) void k_lin(const float* __restrict__ x,
                                             const unsigned short* __restrict__ Wb,
                                             const float* __restrict__ embB,
                                             const float* __restrict__ attnB,
                                             const float* __restrict__ thrW,
                                             const float* __restrict__ thrB,
                                             unsigned short* __restrict__ embb,
                                             float* __restrict__ sq2,
                                             unsigned short* __restrict__ scT,
                                             float* __restrict__ T2out) {
  __shared__ union {
    struct { unsigned short xs[64][40]; unsigned short ws[320][40]; } a;
    unsigned short St[256][72];
  } sm;
  const int t = threadIdx.x;
  const int Mbase = blockIdx.x * 64;
  const int lane = t & 63, wave = t >> 6;
  const int wm = wave >> 1, wn = wave & 1;
  const int l15 = lane & 15, quad = lane >> 4;

  f32x4 acc[2][10] = {};
  for (int k0 = 0; k0 < 256; k0 += 32) {
    { // stage x tile (64x32) from fp32, convert inline
      int row = t >> 2, c0 = (t & 3) * 8;
      const float* src = x + (size_t)(Mbase + row) * 256 + k0 + c0;
      float4 a = *(const float4*)src;
      float4 b = *(const float4*)(src + 4);
      uint4 p; p.x = pack2(a.x, a.y); p.y = pack2(a.z, a.w);
      p.z = pack2(b.x, b.y); p.w = pack2(b.z, b.w);
      *(uint4*)&sm.a.xs[row][c0] = p;
    }
    { // stage weight tile (320x32): pure copies from pre-converted Wb
      const unsigned short* wsrc = Wb + (size_t)t * 256 + k0;
      for (int s = 0; s < 4; s++)
        *(uint4*)&sm.a.ws[t][s * 8] = *(const uint4*)(wsrc + s * 8);
      if (t < 64) {
        const unsigned short* wsrc2 = Wb + (size_t)(256 + t) * 256 + k0;
        for (int s = 0; s < 4; s++)
          *(uint4*)&sm.a.ws[256 + t][s * 8] = *(const uint4*)(wsrc2 + s * 8);
      }
    }
    __syncthreads();
    bf16x8 af[2];
    af[0] = *(const bf16x8*)&sm.a.xs[wm * 32 + l15][quad * 8];
    af[1] = *(const bf16x8*)&sm.a.xs[wm * 32 + 16 + l15][quad * 8];
    for (int nt = 0; nt < 10; nt++) {
      bf16x8 bfr = *(const bf16x8*)&sm.a.ws[wn * 160 + nt * 16 + l15][quad * 8];
      acc[0][nt] = mfma16(af[0], bfr, acc[0][nt]);
      acc[1][nt] = mfma16(af[1], bfr, acc[1][nt]);
    }
    __syncthreads();
  }

  // emb epilogue: wn==0 waves own n<64 (nt 0..3); sq2 from ROUNDED emb.
  if (wn == 0) {
    float sp[2][4] = {{0.f,0.f,0.f,0.f},{0.f,0.f,0.f,0.f}};
    for (int rt = 0; rt < 2; rt++)
      for (int nt = 0; nt < 4; nt++) {
        int n = nt * 16 + l15;
        float bias = embB[n];
        for (int r = 0; r < 4; r++) {
          float v = acc[rt][nt][r] + bias;
          unsigned short hb = f2bf(v);
          int row = wm * 32 + rt * 16 + quad * 4 + r;
          embb[(size_t)(Mbase + row) * 64 + n] = hb;
          float vf = bf2f(hb);
          sp[rt][r] += vf * vf;
        }
      }
    for (int m = 8; m >= 1; m >>= 1)
      for (int rt = 0; rt < 2; rt++)
        for (int r = 0; r < 4; r++)
          sp[rt][r] += __shfl_xor(sp[rt][r], m);
    if (l15 == 0)
      for (int rt = 0; rt < 2; rt++)
        for (int r = 0; r < 4; r++)
          sq2[Mbase + wm * 32 + rt * 16 + quad * 4 + r] = sp[rt][r] * LOG2E;
  }

  // shortcut epilogue -> St transpose buffer
  for (int rt = 0; rt < 2; rt++)
    for (int nt = 0; nt < 10; nt++) {
      int n = wn * 160 + nt * 16 + l15;
      if (n < 64) continue;
      int c = n - 64;
      float bias = attnB[c];
      for (int r = 0; r < 4; r++) {
        float v = acc[rt][nt][r] + bias;
        sm.St[c][wm * 32 + rt * 16 + quad * 4 + r] = f2bf(v);
      }
    }
  __syncthreads();

  const int b = Mbase >> 10, jbase = Mbase & 1023;
  { // coalesced write of scT[b][c][jbase..jbase+64)
    unsigned short* dst = scT + ((size_t)b * 256 + t) * 1024 + jbase;
    for (int s = 0; s < 8; s++)
      *(uint4*)(dst + s * 8) = *(const uint4*)&sm.St[t][s * 8];
  }
  { // Tinst (pre-scaled by log2e)
    float tp = 0.f;
    int j = t >> 2, cs = (t & 3) * 64;
    for (int c = 0; c < 64; c++)
      tp += bf2f(sm.St[cs + c][j]) * thrW[cs + c];
    tp += __shfl_xor(tp, 1);
    tp += __shfl_xor(tp, 2);
    if ((t & 3) == 0) T2out[Mbase + j] = (tp + thrB[0]) * LOG2E;
  }
}

// ---------------------------------------------------------------- k_out2
// Fused R + scores + PV. grid 1024 = 32 row-tiles(32) x 32 b (b = bid&31 ->
// batch->XCD locality), block 256 = 4 waves, 4 blocks/CU resident.
// Wave roles: wr = w&1 (row-half: q-rows wr*16..+15), wj = w>>1 (j-half/sub).
// Pass 0: barrier-free j-half sweep (direct-L2 jf loads), gram -> e_chain ->
//         rp; R = rtmp[0][q] + rtmp[1][q] via LDS (1 barrier).
// Pass 2: 32 steps of 32 j. Each wave: produce its 16-row x 16-j P quadrant
//         (direct-L2 jf, 2 gram MFMA, 4 e/u chains) -> Pb[cur]; barrier;
//         STAGE_S(next); PV 8 MFMA (all rows x its col-quarter).
__global__ __launch_bounds__(256, 4) void k_out2(const unsigned short* __restrict__ embb,
                                                 const float* __restrict__ sq2,
                                                 const float* __restrict__ T2,
                                                 const unsigned short* __restrict__ scT,
                                                 const float* __restrict__ x,
                                                 float* __restrict__ out) {
  __shared__ unsigned short Sb[2][1024 * 8];    // scT step-tile, 16KB x2
  __shared__ unsigned short Pb[2][32 * 40];     // P quadrants, pad-40, dbuf
  __shared__ float rtmp[2][32];                 // R halves
  __shared__ float zsum[2][32];                 // z halves
  const int t = threadIdx.x, lane = t & 63, w = t >> 6;
  const int l15 = lane & 15, quad = lane >> 4;
  const int wr = w & 1, wj = w >> 1;
  const int b = blockIdx.x & 31, rt = blockIdx.x >> 5;   // batch->XCD locality
  const unsigned short* eb = embb + (size_t)b * 1024 * 64;
  const float* sq2b = sq2 + b * 1024;
  const float* T2b = T2 + b * 1024;

  // per-lane fixed gram state: q-row gi (B-operand col = l15)
  const int qrow = wr * 16 + l15;               // 0..31 in block
  const int gi = rt * 32 + qrow;                // 0..1023 in batch
  bf16x8 qf0 = *(const bf16x8*)(eb + (size_t)gi * 64 + quad * 8);
  bf16x8 qf1 = *(const bf16x8*)(eb + (size_t)gi * 64 + 32 + quad * 8);
  const float nsq2q = -sq2b[gi];
  const int yi = gi >> 5, xi = gi & 31;

  const unsigned short* srow = scT + ((size_t)b * 256 + t) * 1024;
#define STAGE_S(bufi, j0s)                                                   \
  do {                                                                       \
    load_lds16(srow + (j0s), &Sb[bufi][(0 * 256 + t) * 8]);                  \
    load_lds16(srow + (j0s) + 8, &Sb[bufi][(1 * 256 + t) * 8]);              \
    load_lds16(srow + (j0s) + 16, &Sb[bufi][(2 * 256 + t) * 8]);             \
    load_lds16(srow + (j0s) + 24, &Sb[bufi][(3 * 256 + t) * 8]);             \
  } while (0)

  STAGE_S(0, 0);   // in flight during pass 0; drained by pass-0-end barrier

  // =================== pass 0: R (barrier-free j-half sweep) ==============
  float rp = 0.f;
  const int jq = wj * 512;
  #pragma unroll 2
  for (int it = 0; it < 16; ++it) {
    const int j0 = jq + it * 32;
    const unsigned short* jr0 = eb + (size_t)(j0 + l15) * 64;
    const unsigned short* jr1 = eb + (size_t)(j0 + 16 + l15) * 64;
    bf16x8 a00 = *(const bf16x8*)(jr0 + quad * 8);
    bf16x8 a01 = *(const bf16x8*)(jr0 + 32 + quad * 8);
    bf16x8 a10 = *(const bf16x8*)(jr1 + quad * 8);
    bf16x8 a11 = *(const bf16x8*)(jr1 + 32 + quad * 8);
    f32x4 g0 = {0.f, 0.f, 0.f, 0.f}, g1 = {0.f, 0.f, 0.f, 0.f};
    g0 = mfma16(a00, qf0, g0);
    g0 = mfma16(a01, qf1, g0);
    g1 = mfma16(a10, qf0, g1);
    g1 = mfma16(a11, qf1, g1);
    #pragma unroll
    for (int jt = 0; jt < 2; ++jt) {
      const f32x4 g = jt ? g1 : g0;
      const int jg = j0 + jt * 16 + quad * 4;
      const float4 s4 = *(const float4*)(sq2b + jg);
      const int dy = iabs(yi - (jg >> 5));
      const int dxa = xi - (jg & 31);
      float e0 = e_chain(g[0], nsq2q, s4.x, dy + iabs(dxa));
      float e1 = e_chain(g[1], nsq2q, s4.y, dy + iabs(dxa - 1));
      float e2 = e_chain(g[2], nsq2q, s4.z, dy + iabs(dxa - 2));
      float e3 = e_chain(g[3], nsq2q, s4.w, dy + iabs(dxa - 3));
      rp += (e0 + e1) + (e2 + e3);
    }
  }
  rp += __shfl_xor(rp, 16);
  rp += __shfl_xor(rp, 32);
  if (quad == 0) rtmp[wj][qrow] = rp;
  __syncthreads();   // rtmp ready; STAGE_S(0) drained (implicit vmcnt 0)
  // both waves sharing a q-row compute this identically (same order):
  const float invR2 = LOG2E / (rtmp[0][qrow] + rtmp[1][qrow]);

  // =================== pass 2: produce P quadrant + PV ====================
  f32x4 acc[2][4] = {};
  float zloc = 0.f;
  #pragma unroll 2
  for (int it = 0; it < 32; ++it) {
    const int cur = it & 1;
    const int j0 = it * 32;

    // ---- produce this wave's 16-row x 16-j quadrant of P[it]
    const int jp = j0 + wj * 16;                 // wave's j-sub base
    const unsigned short* jr = eb + (size_t)(jp + l15) * 64;
    bf16x8 a0 = *(const bf16x8*)(jr + quad * 8);
    bf16x8 a1 = *(const bf16x8*)(jr + 32 + quad * 8);
    f32x4 g = {0.f, 0.f, 0.f, 0.f};
    g = mfma16(a0, qf0, g);                      // row=j (quad*4+r), col=q (l15)
    g = mfma16(a1, qf1, g);
    {
      const int jg = jp + quad * 4;
      const float4 s4 = *(const float4*)(sq2b + jg);
      const float4 t4 = *(const float4*)(T2b + jg);
      const int dy = iabs(yi - (jg >> 5));
      const int dxa = xi - (jg & 31);
      float e0 = e_chain(g[0], nsq2q, s4.x, dy + iabs(dxa));
      float e1 = e_chain(g[1], nsq2q, s4.y, dy + iabs(dxa - 1));
      float e2 = e_chain(g[2], nsq2q, s4.z, dy + iabs(dxa - 2));
      float e3 = e_chain(g[3], nsq2q, s4.w, dy + iabs(dxa - 3));
      float u0 = exp2x(fmaxf(fmaf(e0, invR2, -t4.x), 0.f));
      float u1 = exp2x(fmaxf(fmaf(e1, invR2, -t4.y), 0.f));
      float u2 = exp2x(fmaxf(fmaf(e2, invR2, -t4.z), 0.f));
      float u3 = exp2x(fmaxf(fmaf(e3, invR2, -t4.w), 0.f));
      unsigned pk0 = cvtpk(u0, u1);
      unsigned pk1 = cvtpk(u2, u3);
      // z sums the ROUNDED u used by the GEMM
      zloc += __uint_as_float(pk0 << 16) + __uint_as_float(pk0 & 0xffff0000u);
      zloc += __uint_as_float(pk1 << 16) + __uint_as_float(pk1 & 0xffff0000u);
      uint2 pk; pk.x = pk0; pk.y = pk1;
      *(uint2*)&Pb[cur][qrow * 40 + wj * 16 + quad * 4] = pk;
    }
    __syncthreads();   // Pb[cur] complete; prior-step Sb/Pb reads all done

    // ---- prefetch next scT tile AFTER the barrier (race-free vs PV(it-1))
    if (it < 31) STAGE_S(cur ^ 1, j0 + 32);

    // ---- PV: acc[i][n] += P(rows i*16+l15, k=j) x scT(cols w*64+n*16+l15)
    bf16x8 af[2], bfv[4];
    #pragma unroll
    for (int i = 0; i < 2; i++)
      af[i] = *(const bf16x8*)&Pb[cur][(i * 16 + l15) * 40 + quad * 8];
    #pragma unroll
    for (int n = 0; n < 4; n++)
      bfv[n] = *(const bf16x8*)&Sb[cur][(quad * 256 + w * 64 + n * 16 + l15) * 8];
    #pragma unroll
    for (int i = 0; i < 2; i++)
      #pragma unroll
      for (int n = 0; n < 4; n++)
        acc[i][n] = mfma16(af[i], bfv[n], acc[i][n]);
  }
#undef STAGE_S

  // ---- z handoff (two j-halves per row) + epilogue
  zloc += __shfl_xor(zloc, 16);
  zloc += __shfl_xor(zloc, 32);
  if (quad == 0) zsum[wj][qrow] = zloc;
  __syncthreads();

  #pragma unroll
  for (int i = 0; i < 2; i++) {
    const int rowl = i * 16 + quad * 4;
    float iz[4];
    #pragma unroll
    for (int r = 0; r < 4; r++)
      iz[r] = 1.f / (zsum[0][rowl + r] + zsum[1][rowl + r]);
    const int grow = b * 1024 + rt * 32 + rowl;
    #pragma unroll
    for (int n = 0; n < 4; n++) {
      const int c = w * 64 + n * 16 + l15;
      #pragma unroll
      for (int r = 0; r < 4; r++) {
        size_t idx = (size_t)(grow + r) * 256 + c;
        out[idx] = x[idx] + acc[i][n][r] * iz[r];
      }
    }
  }
}

// ---------------------------------------------------------------- launch
extern "C" void kernel_launch(void* const* d_in, const int* in_sizes, int n_in,
                              void* d_out, int out_size, void* d_ws, size_t ws_size,
                              hipStream_t stream) {
  const float* x     = (const float*)d_in[0];
  const float* embW  = (const float*)d_in[1];
  const float* embB  = (const float*)d_in[2];
  const float* attnW = (const float*)d_in[3];
  const float* attnB = (const float*)d_in[4];
  const float* thrW  = (const float*)d_in[5];
  const float* thrB  = (const float*)d_in[6];
  float* out = (float*)d_out;

  char* ws = (char*)d_ws;
  // layout: embb 4MB | scT 16MB | Wb 160KB | sq2/T2 tail
  unsigned short* embb = (unsigned short*)(ws);
  unsigned short* scT  = (unsigned short*)(ws + (4ull << 20));
  unsigned short* Wb   = (unsigned short*)(ws + (20ull << 20));
  float* sq2 = (float*)(ws + (84ull << 20));
  float* T2  = (float*)(ws + (84ull << 20) + (128ull << 10));

  k_prep<<<80, 256, 0, stream>>>(embW, attnW, Wb);
  k_lin<<<512, 256, 0, stream>>>(x, Wb, embB, attnB, thrW, thrB, embb, sq2, scT, T2);
  k_out2<<<1024, 256, 0, stream>>>(embb, sq2, T2, scT, x, out);
}

// Round 7
// 198.654 us; speedup vs baseline: 1.3057x; 1.3057x over previous
//
#include <hip/hip_runtime.h>
#include <hip/hip_bf16.h>

// InstanceAttentionModule: B=32, H=W=32 (HW=1024), C=256, F=64, K_NEIGH=32.
// Round-15: REVERT k_scores/k_out to the proven round-8 source (193.3us).
// Only k_prep/k_lin change, attacking the never-measured non-attention half:
//   k_prep  : +1 block computes thrV = attnW^T @ thrW and tconst =
//             attnB.thrW + thrB (Tinst is a rank-1 fold: Tinst = x.thrV + c)
//   k_lin   : Tinst accumulated INLINE during x staging (8 fma/k-step on
//             register-resident data) -> the 64-iter bank-conflicted scalar
//             LDS dot product epilogue is DELETED. St transpose writes
//             packed as uint2 (48 scalar ds_write_u16 -> 12 vector writes).
// k_scores, k_out: byte-identical to the 193.3us baseline.

typedef short bf16x8 __attribute__((ext_vector_type(8)));
typedef float f32x4 __attribute__((ext_vector_type(4)));

__device__ __forceinline__ unsigned short f2bf(float f) {
  unsigned u = __float_as_uint(f);
  u += 0x7fffu + ((u >> 16) & 1u);   // round-to-nearest-even
  return (unsigned short)(u >> 16);
}
__device__ __forceinline__ float bf2f(unsigned short h) {
  return __uint_as_float(((unsigned)h) << 16);
}
__device__ __forceinline__ unsigned pack2(float a, float b) {
  return (unsigned)f2bf(a) | ((unsigned)f2bf(b) << 16);
}
__device__ __forceinline__ f32x4 mfma16(bf16x8 a, bf16x8 b, f32x4 c) {
  return __builtin_amdgcn_mfma_f32_16x16x32_bf16(a, b, c, 0, 0, 0);
}
__device__ __forceinline__ int iabs(int v) { return v < 0 ? -v : v; }
__device__ __forceinline__ void load_lds16(const void* g, void* l) {
  __builtin_amdgcn_global_load_lds(
      (const __attribute__((address_space(1))) unsigned int*)g,
      (__attribute__((address_space(3))) unsigned int*)l, 16, 0, 0);
}

// ---------------------------------------------------------------- k_prep
// grid 81 x 256. Blocks 0..79: Wb = bf16(embW || attnW), 4 elems/thread.
// Block 80: thrV[c] = sum_d attnW[d][c]*thrW[d]; thrV[256] = tconst.
__global__ __launch_bounds__(256) void k_prep(const float* __restrict__ embW,
                                              const float* __restrict__ attnW,
                                              const float* __restrict__ attnB,
                                              const float* __restrict__ thrW,
                                              const float* __restrict__ thrB,
                                              unsigned short* __restrict__ Wb,
                                              float* __restrict__ thrV) {
  if (blockIdx.x < 80) {
    const int i = (blockIdx.x * 256 + threadIdx.x) * 4;   // 0..81916
    float4 v = (i < 16384) ? *(const float4*)(embW + i)
                           : *(const float4*)(attnW + (i - 16384));
    ushort4 p; p.x = f2bf(v.x); p.y = f2bf(v.y); p.z = f2bf(v.z); p.w = f2bf(v.w);
    *(ushort4*)(Wb + i) = p;
  } else {
    const int c = threadIdx.x;
    float acc = 0.f;
    for (int d = 0; d < 256; d += 4) {
      float4 tw = *(const float4*)(thrW + d);
      acc += attnW[(size_t)d * 256 + c] * tw.x;
      acc += attnW[(size_t)(d + 1) * 256 + c] * tw.y;
      acc += attnW[(size_t)(d + 2) * 256 + c] * tw.z;
      acc += attnW[(size_t)(d + 3) * 256 + c] * tw.w;
    }
    thrV[c] = acc;
    // tconst = sum_d attnB[d]*thrW[d] + thrB
    float tc = attnB[c] * thrW[c];
    for (int m = 32; m >= 1; m >>= 1) tc += __shfl_xor(tc, m);
    __shared__ float red[4];
    if ((c & 63) == 0) red[c >> 6] = tc;
    __syncthreads();
    if (c == 0) thrV[256] = red[0] + red[1] + red[2] + red[3] + thrB[0];
  }
}

// ---------------------------------------------------------------- k_lin
// Fused emb+shortcut GEMM (N=320). grid 512 (64-row M-tiles), block 256 =
// 4 waves (2x2). Tinst folded into the x-staging loop via thrV.
__global__ __launch_bounds__(256) void k_lin(const float* __restrict__ x,
                                             const unsigned short* __restrict__ Wb,
                                             const float* __restrict__ embB,
                                             const float* __restrict__ attnB,
                                             const float* __restrict__ thrV,
                                             unsigned short* __restrict__ embb,
                                             float* __restrict__ sq,
                                             unsigned short* __restrict__ scT,
                                             float* __restrict__ Tout) {
  __shared__ union {
    struct { unsigned short xs[64][40]; unsigned short ws[320][40]; } a;
    unsigned short St[256][72];
  } sm;
  const int t = threadIdx.x;
  const int Mbase = blockIdx.x * 64;
  const int lane = t & 63, wave = t >> 6;
  const int wm = wave >> 1, wn = wave & 1;
  const int l15 = lane & 15, quad = lane >> 4;

  f32x4 acc[2][10] = {};
  float tp = 0.f;                        // inline Tinst partial (row t>>2)
  for (int k0 = 0; k0 < 256; k0 += 32) {
    { // stage x tile (64x32) from fp32, convert inline; accumulate Tinst
      int row = t >> 2, c0 = (t & 3) * 8;
      const float* src = x + (size_t)(Mbase + row) * 256 + k0 + c0;
      float4 a = *(const float4*)src;
      float4 b = *(const float4*)(src + 4);
      float4 w0 = *(const float4*)(thrV + k0 + c0);
      float4 w1 = *(const float4*)(thrV + k0 + c0 + 4);
      tp += a.x * w0.x + a.y * w0.y + a.z * w0.z + a.w * w0.w
          + b.x * w1.x + b.y * w1.y + b.z * w1.z + b.w * w1.w;
      uint4 p; p.x = pack2(a.x, a.y); p.y = pack2(a.z, a.w);
      p.z = pack2(b.x, b.y); p.w = pack2(b.z, b.w);
      *(uint4*)&sm.a.xs[row][c0] = p;
    }
    { // stage weight tile (320x32): pure copies from pre-converted Wb
      const unsigned short* wsrc = Wb + (size_t)t * 256 + k0;
      for (int s = 0; s < 4; s++)
        *(uint4*)&sm.a.ws[t][s * 8] = *(const uint4*)(wsrc + s * 8);
      if (t < 64) {
        const unsigned short* wsrc2 = Wb + (size_t)(256 + t) * 256 + k0;
        for (int s = 0; s < 4; s++)
          *(uint4*)&sm.a.ws[256 + t][s * 8] = *(const uint4*)(wsrc2 + s * 8);
      }
    }
    __syncthreads();
    bf16x8 af[2];
    af[0] = *(const bf16x8*)&sm.a.xs[wm * 32 + l15][quad * 8];
    af[1] = *(const bf16x8*)&sm.a.xs[wm * 32 + 16 + l15][quad * 8];
    for (int nt = 0; nt < 10; nt++) {
      bf16x8 bfr = *(const bf16x8*)&sm.a.ws[wn * 160 + nt * 16 + l15][quad * 8];
      acc[0][nt] = mfma16(af[0], bfr, acc[0][nt]);
      acc[1][nt] = mfma16(af[1], bfr, acc[1][nt]);
    }
    __syncthreads();
  }

  // Tinst epilogue: reduce the 4 col-slice partials of each row, write.
  {
    tp += __shfl_xor(tp, 1);
    tp += __shfl_xor(tp, 2);
    if ((t & 3) == 0) Tout[Mbase + (t >> 2)] = tp + thrV[256];
  }

  // emb epilogue: wn==0 waves own n<64 (nt 0..3); sq from ROUNDED emb.
  if (wn == 0) {
    float sp[2][4] = {{0.f,0.f,0.f,0.f},{0.f,0.f,0.f,0.f}};
    for (int rt = 0; rt < 2; rt++)
      for (int nt = 0; nt < 4; nt++) {
        int n = nt * 16 + l15;
        float bias = embB[n];
        for (int r = 0; r < 4; r++) {
          float v = acc[rt][nt][r] + bias;
          unsigned short hb = f2bf(v);
          int row = wm * 32 + rt * 16 + quad * 4 + r;
          embb[(size_t)(Mbase + row) * 64 + n] = hb;
          float vf = bf2f(hb);
          sp[rt][r] += vf * vf;
        }
      }
    for (int m = 8; m >= 1; m >>= 1)
      for (int rt = 0; rt < 2; rt++)
        for (int r = 0; r < 4; r++)
          sp[rt][r] += __shfl_xor(sp[rt][r], m);
    if (l15 == 0)
      for (int rt = 0; rt < 2; rt++)
        for (int r = 0; r < 4; r++)
          sq[Mbase + wm * 32 + rt * 16 + quad * 4 + r] = sp[rt][r];
  }

  // shortcut epilogue -> St transpose buffer (packed uint2 writes)
  for (int rt = 0; rt < 2; rt++)
    for (int nt = 0; nt < 10; nt++) {
      int n = wn * 160 + nt * 16 + l15;
      if (n < 64) continue;
      int c = n - 64;
      float bias = attnB[c];
      int base = wm * 32 + rt * 16 + quad * 4;
      uint2 pk;
      pk.x = pack2(acc[rt][nt][0] + bias, acc[rt][nt][1] + bias);
      pk.y = pack2(acc[rt][nt][2] + bias, acc[rt][nt][3] + bias);
      *(uint2*)&sm.St[c][base] = pk;
    }
  __syncthreads();

  const int b = Mbase >> 10, jbase = Mbase & 1023;
  { // coalesced write of scT[b][c][jbase..jbase+64)
    unsigned short* dst = scT + ((size_t)b * 256 + t) * 1024 + jbase;
    for (int s = 0; s < 8; s++)
      *(uint4*)(dst + s * 8) = *(const uint4*)&sm.St[t][s * 8];
  }
}

// ---------------------------------------------------------------- k_scores
// grid 2048 (32 b x 64 strips of 16 rows), block 512 = 8 waves.
// Pass 1: wave w owns j-eighth [w*128,(w+1)*128); gram MFMA -> E in LDS + R.
// Pass 2: thread (row=t>>5, seg=t&31): u = exp(relu(E/R - T)) -> U, Z.
// (byte-identical to the 193.3us baseline)
__global__ __launch_bounds__(512) void k_scores(const unsigned short* __restrict__ embb,
                                                const float* __restrict__ sq,
                                                const float* __restrict__ T,
                                                unsigned short* __restrict__ U,
                                                float* __restrict__ Z) {
  __shared__ unsigned short E_lds[16 * 1040];   // 33280 B
  __shared__ float rbuf[16];
  __shared__ float mtab[64];                    // exp(m(diff) - 1), diff 0..62
  const int t = threadIdx.x, lane = t & 63, wave = t >> 6;
  const int b = blockIdx.x >> 6, rb = (blockIdx.x & 63) * 16;
  const int l15 = lane & 15, quad = lane >> 4;
  const unsigned short* eb = embb + (size_t)b * 1024 * 64;

  if (t < 16) rbuf[t] = 0.f;
  if (t < 64) {
    float m = (t <= 32) ? (float)t * (1.f / 32.f) : 0.f;
    mtab[t] = __expf(m - 1.f);
  }
  __syncthreads();   // mtab + rbuf visible

  // ---- pass 1 (wave w: j in [w*128, w*128+128))
  const int rowA = rb + l15;
  bf16x8 a0 = *(const bf16x8*)(eb + (size_t)rowA * 64 + quad * 8);
  bf16x8 a1 = *(const bf16x8*)(eb + (size_t)rowA * 64 + 32 + quad * 8);
  const int rloc = quad * 4;
  // rows rloc..rloc+3 share y (4 | 32): hoist per-thread coords
  const int yi0 = (rb + rloc) >> 5, xi0 = (rb + rloc) & 31;
  float nsqi[4];
  for (int r = 0; r < 4; r++) nsqi[r] = -sq[b * 1024 + rb + rloc + r];
  const int jq = wave * 128;
  float rp[4] = {0.f, 0.f, 0.f, 0.f};
  for (int j0 = jq; j0 < jq + 128; j0 += 16) {
    const int jr = j0 + l15;
    bf16x8 b0 = *(const bf16x8*)(eb + (size_t)jr * 64 + quad * 8);
    bf16x8 b1 = *(const bf16x8*)(eb + (size_t)jr * 64 + 32 + quad * 8);
    f32x4 g = {0.f, 0.f, 0.f, 0.f};
    g = mfma16(a0, b0, g);
    g = mfma16(a1, b1, g);
    float sqj = sq[b * 1024 + jr];
    int dy = iabs(yi0 - (jr >> 5));
    int dxa = xi0 - (jr & 31);
    for (int r = 0; r < 4; r++) {
      float w = fminf(fmaf(2.f, g[r], nsqi[r] - sqj), 0.f);  // -d2, <= 0
      float v = __expf(w);                                    // exp(-d2)
      int diff = dy + iabs(dxa + r);
      float e = __expf(v) * mtab[diff];                       // exp(v - 1 + m)
      E_lds[(rloc + r) * 1040 + jr] = f2bf(e);
      rp[r] += e;   // unrounded sum: rel err ~1e-4 on R, damped in u
    }
  }
  for (int m = 8; m >= 1; m >>= 1)
    for (int r = 0; r < 4; r++)
      rp[r] += __shfl_xor(rp[r], m);
  __syncthreads();   // E_lds writes complete
  if (l15 == 0)
    for (int r = 0; r < 4; r++)
      atomicAdd(&rbuf[rloc + r], rp[r]);
  __syncthreads();   // R complete

  // ---- pass 2: row = t>>5 (0..15), seg = t&31 (0..31)
  const int prow = t >> 5, seg = t & 31;
  const float invR = 1.f / rbuf[prow];
  const float* Tb = T + b * 1024;
  unsigned short* ur = U + ((size_t)(b * 1024 + rb + prow)) * 1024;
  float z = 0.f;
  for (int c = 0; c < 4; c++) {
    int j = c * 256 + seg * 8;
    union { bf16x8 v; unsigned short s[8]; } ev;
    ev.v = *(const bf16x8*)&E_lds[prow * 1040 + j];
    float4 t0 = *(const float4*)(Tb + j);
    float4 t1 = *(const float4*)(Tb + j + 4);
    float tf[8] = {t0.x, t0.y, t0.z, t0.w, t1.x, t1.y, t1.z, t1.w};
    union { uint4 v; unsigned short s[8]; } uo;
    for (int k = 0; k < 8; k++) {
      float u = __expf(fmaxf(fmaf(bf2f(ev.s[k]), invR, -tf[k]), 0.f));
      unsigned short h = f2bf(u);
      uo.s[k] = h;
      z += bf2f(h);   // Z sums the ROUNDED u used by the GEMM
    }
    *(uint4*)(ur + j) = uo.v;
  }
  z += __shfl_xor(z, 1);
  z += __shfl_xor(z, 2);
  z += __shfl_xor(z, 4);
  z += __shfl_xor(z, 8);
  z += __shfl_xor(z, 16);
  if (seg == 0) Z[b * 1024 + rb + prow] = z;
}

// ---------------------------------------------------------------- k_out
// m97-style GEMM: out = x + (U @ scT^T) * invZ.  (baseline version)
__global__ __launch_bounds__(256) void k_out(const unsigned short* __restrict__ U,
                                             const float* __restrict__ Z,
                                             const unsigned short* __restrict__ scT,
                                             const float* __restrict__ x,
                                             float* __restrict__ out) {
  __shared__ unsigned short Ab[128 * 32];
  __shared__ unsigned short Bb[128 * 32];
  const int t = threadIdx.x, lane = t & 63, wave = t >> 6;
  const int wm = wave >> 1, wn = wave & 1;
  const int l15 = lane & 15, quad = lane >> 4;
  const int x8 = blockIdx.x & 7, s = blockIdx.x >> 3;
  const int b = x8 * 4 + (s >> 4), tile = s & 15;
  const int rb = (tile >> 1) * 128, cb = (tile & 1) * 128;

  const unsigned short* Ubase = U + (size_t)b * 1024 * 1024 + (size_t)rb * 1024;
  const unsigned short* Sbase = scT + (size_t)b * 256 * 1024 + (size_t)cb * 1024;

  int c0 = wave * 64 + lane;
  int c1 = c0 + 256;
  const int r0 = c0 >> 2, o0 = (c0 & 3) * 8;
  const int r1 = c1 >> 2, o1 = (c1 & 3) * 8;

  f32x4 acc[4][4] = {};
  for (int j0 = 0; j0 < 1024; j0 += 32) {
    load_lds16(Ubase + (size_t)r0 * 1024 + j0 + o0, Ab + c0 * 8);
    load_lds16(Ubase + (size_t)r1 * 1024 + j0 + o1, Ab + c1 * 8);
    load_lds16(Sbase + (size_t)r0 * 1024 + j0 + o0, Bb + c0 * 8);
    load_lds16(Sbase + (size_t)r1 * 1024 + j0 + o1, Bb + c1 * 8);
    __syncthreads();
    bf16x8 af[4], bf[4];
    for (int i = 0; i < 4; i++)
      af[i] = *(const bf16x8*)&Ab[(wm * 64 + i * 16 + l15) * 32 + quad * 8];
    for (int i = 0; i < 4; i++)
      bf[i] = *(const bf16x8*)&Bb[(wn * 64 + i * 16 + l15) * 32 + quad * 8];
    for (int i = 0; i < 4; i++)
      for (int j = 0; j < 4; j++)
        acc[i][j] = mfma16(af[i], bf[j], acc[i][j]);
    __syncthreads();
  }

  const int colb = cb + wn * 64;
  for (int i = 0; i < 4; i++) {
    int rowb = rb + wm * 64 + i * 16 + quad * 4;
    float iz[4];
    for (int r = 0; r < 4; r++) iz[r] = 1.f / Z[b * 1024 + rowb + r];
    for (int j = 0; j < 4; j++) {
      int c = colb + j * 16 + l15;
      for (int r = 0; r < 4; r++) {
        size_t idx = ((size_t)(b * 1024 + rowb + r)) * 256 + c;
        out[idx] = x[idx] + acc[i][j][r] * iz[r];
      }
    }
  }
}

// ---------------------------------------------------------------- launch
extern "C" void kernel_launch(void* const* d_in, const int* in_sizes, int n_in,
                              void* d_out, int out_size, void* d_ws, size_t ws_size,
                              hipStream_t stream) {
  const float* x     = (const float*)d_in[0];
  const float* embW  = (const float*)d_in[1];
  const float* embB  = (const float*)d_in[2];
  const float* attnW = (const float*)d_in[3];
  const float* attnB = (const float*)d_in[4];
  const float* thrW  = (const float*)d_in[5];
  const float* thrB  = (const float*)d_in[6];
  float* out = (float*)d_out;

  char* ws = (char*)d_ws;
  // layout: embb 4MB | scT 16MB | U 64MB | sq/T/Z tail
  // Wb (160KB) and thrV (1.1KB) OVERLAP U: both dead before k_scores writes U.
  unsigned short* embb = (unsigned short*)(ws);
  unsigned short* scT  = (unsigned short*)(ws + (4ull << 20));
  unsigned short* U    = (unsigned short*)(ws + (20ull << 20));
  unsigned short* Wb   = (unsigned short*)(ws + (36ull << 20));            // overlap
  float* thrV = (float*)(ws + (36ull << 20) + (192ull << 10));             // overlap
  float* sq = (float*)(ws + (84ull << 20));
  float* T  = (float*)(ws + (84ull << 20) + (128ull << 10));
  float* Z  = (float*)(ws + (84ull << 20) + (256ull << 10));

  k_prep<<<81, 256, 0, stream>>>(embW, attnW, attnB, thrW, thrB, Wb, thrV);
  k_lin<<<512, 256, 0, stream>>>(x, Wb, embB, attnB, thrV, embb, sq, scT, T);
  k_scores<<<2048, 512, 0, stream>>>(embb, sq, T, U, Z);
  k_out<<<512, 256, 0, stream>>>(U, Z, scT, x, out);
}